// Round 7
// baseline (45.206 us; speedup 1.0000x reference)
//
#include <hip/hip_runtime.h>
#include <hip/hip_bf16.h>
#include <math.h>

#define NA 4096
#define NM 64
#define NQ 64
#define NH 64

// ws layout (floats): PARTT[slot][NA]; slots 0..8 = pm[a*3+c], slot 9 = fpv.
#define WS_FLOATS (10 * NA)

typedef float vf4 __attribute__((ext_vector_type(4)));
__device__ __forceinline__ float4 ntld(const float4* p) {
    vf4 v = __builtin_nontemporal_load(reinterpret_cast<const vf4*>(p));
    return make_float4(v[0], v[1], v[2], v[3]);
}

// ---------------- Main fused kernel: one atom per 256-thread block ----------------
// Waves: 0 = tensor ANN fwd+bwd (wave-internal), 1 = displacement scalars,
// 2 = pol ANN; all 4 waves stream. 6/12 grad float4s per lane preloaded before
// the first barrier so HBM latency hides under the MLP preamble. All grad loads
// non-temporal: zero reuse, keep L2/L3 clean for the weight working set.
__global__ __launch_bounds__(256) void tnep_fused(
    const float* __restrict__ desc,
    const float* __restrict__ grad,
    const int*   __restrict__ gidx,
    const float* __restrict__ pos,
    const int*   __restrict__ Zp,
    const float* __restrict__ box,
    const float* __restrict__ amaskp,
    const float* __restrict__ nmaskp,
    const float* __restrict__ W0,
    const float* __restrict__ b0,
    const float* __restrict__ W1,
    const float* __restrict__ W0p,
    const float* __restrict__ b0p,
    const float* __restrict__ W1p,
    const float* __restrict__ b1p,
    float* __restrict__ ws)
{
    const int n    = blockIdx.x;
    const int tid  = threadIdx.x;
    const int w    = tid >> 6;
    const int lane = tid & 63;
    const int msub = lane >> 4;
    const int q4   = lane & 15;
    const int z    = Zp[n];

    float* PARTT = ws;

    __shared__ float sW0[NQ * 65];   // padded: fwd (stride-1) & bwd (stride-65) conflict-free
    __shared__ float sdesc[NQ];
    __shared__ float sde_da[NH];
    __shared__ float sde_dq[NQ];
    __shared__ float swdr[NM * 4];
    __shared__ float sacc[4][9];
    __shared__ float sfpv;

    // ---- Early preloads: 6 of this lane's 12 grad float4s, in flight across
    // the whole MLP preamble. ----
    const float4* gbase = reinterpret_cast<const float4*>(grad)
                          + ((size_t)n * NM + w * 16 + msub) * 48 + q4;
    float4 p00 = ntld(gbase +   0), p01 = ntld(gbase +  16), p02 = ntld(gbase +  32); // gset 0
    float4 p10 = ntld(gbase + 192), p11 = ntld(gbase + 208), p12 = ntld(gbase + 224); // gset 1

    // Cooperative stage of W0[z] (16 KB), all 256 threads.
    const float4* W0v = reinterpret_cast<const float4*>(W0 + (size_t)z * NQ * NH);
#pragma unroll
    for (int i = 0; i < 4; ++i) {
        int f = i * 256 + tid;
        float4 v = W0v[f];
        int q  = f >> 4;
        int h0 = (f & 15) * 4;
        float* p = &sW0[q * 65 + h0];
        p[0] = v.x; p[1] = v.y; p[2] = v.z; p[3] = v.w;
    }
    if (w == 0) sdesc[lane] = desc[n * NQ + lane];
    if (w == 1) {
        // Minimal-image displacement scalars, -nmask^2 folded in (lane = m).
        int g = gidx[n * NM + lane];
        float Lx = box[0], Ly = box[4], Lz = box[8];
        float dx = pos[g * 3 + 0] - pos[n * 3 + 0];
        float dy = pos[g * 3 + 1] - pos[n * 3 + 1];
        float dz = pos[g * 3 + 2] - pos[n * 3 + 2];
        dx -= Lx * rintf(dx * (1.0f / Lx));   // rintf = round-half-even = jnp.round
        dy -= Ly * rintf(dy * (1.0f / Ly));
        dz -= Lz * rintf(dz * (1.0f / Lz));
        float nm = nmaskp[n * NM + lane];
        float wt = -nm * nm;
        swdr[lane * 4 + 0] = wt * dx;
        swdr[lane * 4 + 1] = wt * dy;
        swdr[lane * 4 + 2] = wt * dz;
        swdr[lane * 4 + 3] = 0.0f;
    }
    __syncthreads();   // B1: sW0, sdesc, swdr ready

    if (w == 0) {
        // Tensor ANN fwd + bwd, entirely within wave 0 (wave-synchronous LDS;
        // DS ops are in-order within a wave, no barrier needed between phases).
        float amask = amaskp[n];
        float a_t = b0[z * NH + lane];
#pragma unroll 8
        for (int q = 0; q < NQ; ++q)
            a_t = fmaf(sdesc[q], sW0[q * 65 + lane], a_t);
        float hT = tanhf(a_t) * amask;
        sde_da[lane] = (1.0f - hT * hT) * W1[z * NH + lane];   // lane = h
        float dq = 0.0f;
#pragma unroll 8
        for (int h = 0; h < NH; ++h)                            // lane = q
            dq = fmaf(sde_da[h], sW0[lane * 65 + h], dq);
        sde_dq[lane] = dq;
    } else if (w == 2) {
        // Pol ANN (global reads only; W0p/desc are L2-resident).
        float amask = amaskp[n];
        float a_p = b0p[z * NH + lane];
        const float* W0prow = W0p + (size_t)z * NQ * NH;
        const float* drow   = desc + (size_t)n * NQ;
#pragma unroll 8
        for (int q = 0; q < NQ; ++q)
            a_p = fmaf(drow[q], W0prow[q * NH + lane], a_p);
        float hP = tanhf(a_p) * amask;
        float fp = hP * W1p[z * NH + lane];
#pragma unroll
        for (int s = 1; s < 64; s <<= 1) fp += __shfl_xor(fp, s, 64);
        if (lane == 0) sfpv = (fp + b1p[0]) * amask;
    }
    __syncthreads();   // B2: sde_dq, sfpv ready

    // ---- Streaming phase: wave w owns m in [w*16, w*16+16); lane = msub*16+q4.
    float4 dq4 = *reinterpret_cast<const float4*>(&sde_dq[4 * q4]);
    float acc[3][3] = {{0.f,0.f,0.f},{0.f,0.f,0.f},{0.f,0.f,0.f}};
    const int mb4 = (w * 16 + msub) * 4;

#define TNEP_DOT(g4) fmaf(dq4.x, (g4).x, fmaf(dq4.y, (g4).y, fmaf(dq4.z, (g4).z, dq4.w * (g4).w)))
#define TNEP_ACC(g0, g1, g2, widx)                                              \
    {                                                                           \
        float wd0 = swdr[(widx) + 0], wd1 = swdr[(widx) + 1], wd2 = swdr[(widx) + 2]; \
        float s0 = TNEP_DOT(g0), s1 = TNEP_DOT(g1), s2 = TNEP_DOT(g2);          \
        acc[0][0] = fmaf(s0, wd0, acc[0][0]);                                   \
        acc[1][0] = fmaf(s0, wd1, acc[1][0]);                                   \
        acc[2][0] = fmaf(s0, wd2, acc[2][0]);                                   \
        acc[0][1] = fmaf(s1, wd0, acc[0][1]);                                   \
        acc[1][1] = fmaf(s1, wd1, acc[1][1]);                                   \
        acc[2][1] = fmaf(s1, wd2, acc[2][1]);                                   \
        acc[0][2] = fmaf(s2, wd0, acc[0][2]);                                   \
        acc[1][2] = fmaf(s2, wd1, acc[1][2]);                                   \
        acc[2][2] = fmaf(s2, wd2, acc[2][2]);                                   \
    }

    TNEP_ACC(p00, p01, p02, mb4);            // gset 0 (preloaded)
    TNEP_ACC(p10, p11, p12, mb4 + 16);       // gset 1 (preloaded)
    {
        float4 g0 = ntld(gbase + 384), g1 = ntld(gbase + 400), g2 = ntld(gbase + 416); // gset 2
        TNEP_ACC(g0, g1, g2, mb4 + 32);
    }
    {
        float4 g0 = ntld(gbase + 576), g1 = ntld(gbase + 592), g2 = ntld(gbase + 608); // gset 3
        TNEP_ACC(g0, g1, g2, mb4 + 48);
    }
#undef TNEP_ACC
#undef TNEP_DOT

    // One 64-lane reduction per wave, then cross-wave via LDS.
#pragma unroll
    for (int a = 0; a < 3; ++a)
#pragma unroll
        for (int c = 0; c < 3; ++c) {
            float v = acc[a][c];
#pragma unroll
            for (int s = 1; s < 64; s <<= 1) v += __shfl_xor(v, s, 64);
            if (lane == 0) sacc[w][a * 3 + c] = v;
        }
    __syncthreads();   // B3: sacc, sfpv ready

    if (tid < 9)
        PARTT[(size_t)tid * NA + n] = sacc[0][tid] + sacc[1][tid] + sacc[2][tid] + sacc[3][tid];
    if (tid == 9)
        PARTT[(size_t)9 * NA + n] = sfpv;
}

// ---------------- Final reduction: 10 waves, one slot each, coalesced ----------------
__global__ __launch_bounds__(640) void tnep_reduce(const float* __restrict__ ws,
                                                   float* __restrict__ out)
{
    __shared__ float sred[10];
    const int w    = threadIdx.x >> 6;
    const int lane = threadIdx.x & 63;

    const float4* p = reinterpret_cast<const float4*>(ws + (size_t)w * NA);
    float s = 0.f;
#pragma unroll
    for (int i = 0; i < 16; ++i) {
        float4 v = p[lane + 64 * i];
        s += (v.x + v.y) + (v.z + v.w);
    }
#pragma unroll
    for (int t = 1; t < 64; t <<= 1) s += __shfl_xor(s, t, 64);
    if (lane == 0) sred[w] = s;
    __syncthreads();
    if (threadIdx.x == 0) {
        float S = sred[9];
        out[0] = sred[0] + S;   // pm00 + scalar
        out[1] = sred[4] + S;   // pm11 + scalar
        out[2] = sred[8] + S;   // pm22 + scalar
        out[3] = sred[1];       // pm01
        out[4] = sred[5];       // pm12
        out[5] = sred[6];       // pm20
    }
}

// ---------------- Fallback (tiny ws): monolithic with atomics ----------------
__global__ __launch_bounds__(64) void tnep_mono(
    const float* __restrict__ desc,
    const float* __restrict__ grad,
    const int*   __restrict__ gidx,
    const float* __restrict__ pos,
    const int*   __restrict__ Zp,
    const float* __restrict__ box,
    const float* __restrict__ amaskp,
    const float* __restrict__ nmaskp,
    const float* __restrict__ W0,
    const float* __restrict__ b0,
    const float* __restrict__ W1,
    const float* __restrict__ W0p,
    const float* __restrict__ b0p,
    const float* __restrict__ W1p,
    const float* __restrict__ b1p,
    float* __restrict__ out)
{
    const int n    = blockIdx.x;
    const int lane = threadIdx.x;
    const int z    = Zp[n];
    const float amask = amaskp[n];

    __shared__ float sdesc[NQ];
    __shared__ float sW0[NQ * 65];
    __shared__ float sde_da[NH];
    __shared__ float sde_dq[NQ];
    __shared__ float sdr[NM * 4];

    sdesc[lane] = desc[n * NQ + lane];
    const float4* W0v = reinterpret_cast<const float4*>(W0 + (size_t)z * NQ * NH);
#pragma unroll
    for (int i = 0; i < 16; ++i) {
        float4 v = W0v[i * 64 + lane];
        int q  = 4 * i + (lane >> 4);
        int h0 = 4 * (lane & 15);
        float* p = &sW0[q * 65 + h0];
        p[0] = v.x; p[1] = v.y; p[2] = v.z; p[3] = v.w;
    }
    {
        int g = gidx[n * NM + lane];
        float Lx = box[0], Ly = box[4], Lz = box[8];
        float dx = pos[g * 3 + 0] - pos[n * 3 + 0];
        float dy = pos[g * 3 + 1] - pos[n * 3 + 1];
        float dz = pos[g * 3 + 2] - pos[n * 3 + 2];
        dx -= Lx * rintf(dx * (1.0f / Lx));
        dy -= Ly * rintf(dy * (1.0f / Ly));
        dz -= Lz * rintf(dz * (1.0f / Lz));
        float nm = nmaskp[n * NM + lane];
        float wt = -nm * nm;
        sdr[lane * 4 + 0] = wt * dx;
        sdr[lane * 4 + 1] = wt * dy;
        sdr[lane * 4 + 2] = wt * dz;
        sdr[lane * 4 + 3] = 0.0f;
    }
    __syncthreads();

    float a_t = b0 [z * NH + lane];
    float a_p = b0p[z * NH + lane];
    const float* W0prow = W0p + (size_t)z * NQ * NH;
#pragma unroll 8
    for (int q = 0; q < NQ; ++q) {
        float d = sdesc[q];
        a_t = fmaf(d, sW0[q * 65 + lane], a_t);
        a_p = fmaf(d, W0prow[q * NH + lane], a_p);
    }
    float hT = tanhf(a_t) * amask;
    float hP = tanhf(a_p) * amask;
    sde_da[lane] = (1.0f - hT * hT) * W1[z * NH + lane];
    float fp = hP * W1p[z * NH + lane];
#pragma unroll
    for (int s = 1; s < 64; s <<= 1) fp += __shfl_xor(fp, s, 64);
    __syncthreads();

    float dq = 0.0f;
#pragma unroll 8
    for (int h = 0; h < NH; ++h)
        dq = fmaf(sde_da[h], sW0[lane * 65 + h], dq);
    sde_dq[lane] = dq;
    __syncthreads();

    const int msub = lane >> 4;
    const int q4   = lane & 15;
    float4 dq4 = *reinterpret_cast<const float4*>(&sde_dq[4 * q4]);
    float acc[3][3] = {{0.f,0.f,0.f},{0.f,0.f,0.f},{0.f,0.f,0.f}};
    const float4* gbase = reinterpret_cast<const float4*>(grad)
                          + (size_t)n * NM * 48 + msub * 48 + q4;
#pragma unroll
    for (int gset = 0; gset < 16; ++gset) {
        const float4* gp = gbase + gset * 192;
        const int m = gset * 4 + msub;
        float wd0 = sdr[m * 4 + 0];
        float wd1 = sdr[m * 4 + 1];
        float wd2 = sdr[m * 4 + 2];
#pragma unroll
        for (int c = 0; c < 3; ++c) {
            float4 g4 = gp[c * 16];
            float s = fmaf(dq4.x, g4.x, fmaf(dq4.y, g4.y, fmaf(dq4.z, g4.z, dq4.w * g4.w)));
            acc[0][c] = fmaf(s, wd0, acc[0][c]);
            acc[1][c] = fmaf(s, wd1, acc[1][c]);
            acc[2][c] = fmaf(s, wd2, acc[2][c]);
        }
    }
    float fpv = (fp + b1p[0]) * amask;
#pragma unroll
    for (int a = 0; a < 3; ++a)
#pragma unroll
        for (int c = 0; c < 3; ++c) {
            float v = acc[a][c];
#pragma unroll
            for (int s = 1; s < 64; s <<= 1) v += __shfl_xor(v, s, 64);
            acc[a][c] = v;
        }
    if (lane == 0) {
        atomicAdd(out + 0, acc[0][0] + fpv);
        atomicAdd(out + 1, acc[1][1] + fpv);
        atomicAdd(out + 2, acc[2][2] + fpv);
        atomicAdd(out + 3, acc[0][1]);
        atomicAdd(out + 4, acc[1][2]);
        atomicAdd(out + 5, acc[2][0]);
    }
}

__global__ void tnep_zero(float* out)
{
    if (threadIdx.x < 6) out[threadIdx.x] = 0.f;
}

extern "C" void kernel_launch(void* const* d_in, const int* in_sizes, int n_in,
                              void* d_out, int out_size, void* d_ws, size_t ws_size,
                              hipStream_t stream)
{
    const float* desc  = (const float*)d_in[0];
    const float* grad  = (const float*)d_in[1];
    const int*   gidx  = (const int*)  d_in[2];
    const float* pos   = (const float*)d_in[3];
    const int*   Zp    = (const int*)  d_in[4];
    const float* box   = (const float*)d_in[5];
    const float* amask = (const float*)d_in[6];
    const float* nmask = (const float*)d_in[7];
    const float* W0    = (const float*)d_in[8];
    const float* b0    = (const float*)d_in[9];
    const float* W1    = (const float*)d_in[10];
    // d_in[11] = b1 (unused by reference)
    const float* W0p   = (const float*)d_in[12];
    const float* b0p   = (const float*)d_in[13];
    const float* W1p   = (const float*)d_in[14];
    const float* b1p   = (const float*)d_in[15];
    float* out = (float*)d_out;
    float* ws  = (float*)d_ws;

    if (ws_size >= (size_t)WS_FLOATS * sizeof(float)) {
        tnep_fused<<<NA, 256, 0, stream>>>(desc, grad, gidx, pos, Zp, box, amask, nmask,
                                           W0, b0, W1, W0p, b0p, W1p, b1p, ws);
        tnep_reduce<<<1, 640, 0, stream>>>(ws, out);
    } else {
        tnep_zero<<<1, 64, 0, stream>>>(out);
        tnep_mono<<<NA, 64, 0, stream>>>(desc, grad, gidx, pos, Zp, box, amask, nmask,
                                         W0, b0, W1, W0p, b0p, W1p, b1p, out);
    }
}

// Round 8
// 44.776 us; speedup vs baseline: 1.0096x; 1.0096x over previous
//
#include <hip/hip_runtime.h>
#include <hip/hip_bf16.h>
#include <math.h>

#define NA 4096
#define NM 64
#define NQ 64
#define NH 64

// ws layout (floats): PARTT[slot][NA]; slots 0..8 = pm[a*3+c], slot 9 = fpv.
#define WS_FLOATS (10 * NA)

// ---------------- Main fused kernel: one atom per 256-thread block ----------------
// Waves: 0 = tensor ANN fwd+bwd (wave-internal), 1 = displacement scalars,
// 2 = pol ANN; all 4 waves stream. 6/12 grad float4s per lane preloaded before
// the first barrier so HBM latency hides under the MLP preamble.
__global__ __launch_bounds__(256) void tnep_fused(
    const float* __restrict__ desc,
    const float* __restrict__ grad,
    const int*   __restrict__ gidx,
    const float* __restrict__ pos,
    const int*   __restrict__ Zp,
    const float* __restrict__ box,
    const float* __restrict__ amaskp,
    const float* __restrict__ nmaskp,
    const float* __restrict__ W0,
    const float* __restrict__ b0,
    const float* __restrict__ W1,
    const float* __restrict__ W0p,
    const float* __restrict__ b0p,
    const float* __restrict__ W1p,
    const float* __restrict__ b1p,
    float* __restrict__ ws)
{
    const int n    = blockIdx.x;
    const int tid  = threadIdx.x;
    const int w    = tid >> 6;
    const int lane = tid & 63;
    const int msub = lane >> 4;
    const int q4   = lane & 15;
    const int z    = Zp[n];

    float* PARTT = ws;

    __shared__ float sW0[NQ * 65];   // padded: fwd (stride-1) & bwd (stride-65) conflict-free
    __shared__ float sdesc[NQ];
    __shared__ float sde_da[NH];
    __shared__ float sde_dq[NQ];
    __shared__ float swdr[NM * 4];
    __shared__ float sacc[4][9];
    __shared__ float sfpv;

    // ---- Early preloads: 6 of this lane's 12 grad float4s, in flight across
    // the whole MLP preamble. ----
    const float4* gbase = reinterpret_cast<const float4*>(grad)
                          + ((size_t)n * NM + w * 16 + msub) * 48 + q4;
    float4 p00 = gbase[0],   p01 = gbase[16],  p02 = gbase[32];    // gset 0, c=0..2
    float4 p10 = gbase[192], p11 = gbase[208], p12 = gbase[224];   // gset 1, c=0..2

    // Cooperative stage of W0[z] (16 KB), all 256 threads.
    const float4* W0v = reinterpret_cast<const float4*>(W0 + (size_t)z * NQ * NH);
#pragma unroll
    for (int i = 0; i < 4; ++i) {
        int f = i * 256 + tid;
        float4 v = W0v[f];
        int q  = f >> 4;
        int h0 = (f & 15) * 4;
        float* p = &sW0[q * 65 + h0];
        p[0] = v.x; p[1] = v.y; p[2] = v.z; p[3] = v.w;
    }
    if (w == 0) sdesc[lane] = desc[n * NQ + lane];
    if (w == 1) {
        // Minimal-image displacement scalars, -nmask^2 folded in (lane = m).
        int g = gidx[n * NM + lane];
        float Lx = box[0], Ly = box[4], Lz = box[8];
        float dx = pos[g * 3 + 0] - pos[n * 3 + 0];
        float dy = pos[g * 3 + 1] - pos[n * 3 + 1];
        float dz = pos[g * 3 + 2] - pos[n * 3 + 2];
        dx -= Lx * rintf(dx * (1.0f / Lx));   // rintf = round-half-even = jnp.round
        dy -= Ly * rintf(dy * (1.0f / Ly));
        dz -= Lz * rintf(dz * (1.0f / Lz));
        float nm = nmaskp[n * NM + lane];
        float wt = -nm * nm;
        swdr[lane * 4 + 0] = wt * dx;
        swdr[lane * 4 + 1] = wt * dy;
        swdr[lane * 4 + 2] = wt * dz;
        swdr[lane * 4 + 3] = 0.0f;
    }
    __syncthreads();   // B1: sW0, sdesc, swdr ready

    if (w == 0) {
        // Tensor ANN fwd + bwd, entirely within wave 0 (wave-synchronous LDS;
        // DS ops are in-order within a wave, no barrier needed between phases).
        float amask = amaskp[n];
        float a_t = b0[z * NH + lane];
#pragma unroll 8
        for (int q = 0; q < NQ; ++q)
            a_t = fmaf(sdesc[q], sW0[q * 65 + lane], a_t);
        float hT = tanhf(a_t) * amask;
        sde_da[lane] = (1.0f - hT * hT) * W1[z * NH + lane];   // lane = h
        float dq = 0.0f;
#pragma unroll 8
        for (int h = 0; h < NH; ++h)                            // lane = q
            dq = fmaf(sde_da[h], sW0[lane * 65 + h], dq);
        sde_dq[lane] = dq;
    } else if (w == 2) {
        // Pol ANN (global reads only; W0p/desc are L2-resident).
        float amask = amaskp[n];
        float a_p = b0p[z * NH + lane];
        const float* W0prow = W0p + (size_t)z * NQ * NH;
        const float* drow   = desc + (size_t)n * NQ;
#pragma unroll 8
        for (int q = 0; q < NQ; ++q)
            a_p = fmaf(drow[q], W0prow[q * NH + lane], a_p);
        float hP = tanhf(a_p) * amask;
        float fp = hP * W1p[z * NH + lane];
#pragma unroll
        for (int s = 1; s < 64; s <<= 1) fp += __shfl_xor(fp, s, 64);
        if (lane == 0) sfpv = (fp + b1p[0]) * amask;
    }
    __syncthreads();   // B2: sde_dq, sfpv ready

    // ---- Streaming phase: wave w owns m in [w*16, w*16+16); lane = msub*16+q4.
    float4 dq4 = *reinterpret_cast<const float4*>(&sde_dq[4 * q4]);
    float acc[3][3] = {{0.f,0.f,0.f},{0.f,0.f,0.f},{0.f,0.f,0.f}};
    const int mb4 = (w * 16 + msub) * 4;

#define TNEP_DOT(g4) fmaf(dq4.x, (g4).x, fmaf(dq4.y, (g4).y, fmaf(dq4.z, (g4).z, dq4.w * (g4).w)))
#define TNEP_ACC(g0, g1, g2, widx)                                              \
    {                                                                           \
        float wd0 = swdr[(widx) + 0], wd1 = swdr[(widx) + 1], wd2 = swdr[(widx) + 2]; \
        float s0 = TNEP_DOT(g0), s1 = TNEP_DOT(g1), s2 = TNEP_DOT(g2);          \
        acc[0][0] = fmaf(s0, wd0, acc[0][0]);                                   \
        acc[1][0] = fmaf(s0, wd1, acc[1][0]);                                   \
        acc[2][0] = fmaf(s0, wd2, acc[2][0]);                                   \
        acc[0][1] = fmaf(s1, wd0, acc[0][1]);                                   \
        acc[1][1] = fmaf(s1, wd1, acc[1][1]);                                   \
        acc[2][1] = fmaf(s1, wd2, acc[2][1]);                                   \
        acc[0][2] = fmaf(s2, wd0, acc[0][2]);                                   \
        acc[1][2] = fmaf(s2, wd1, acc[1][2]);                                   \
        acc[2][2] = fmaf(s2, wd2, acc[2][2]);                                   \
    }

    TNEP_ACC(p00, p01, p02, mb4);            // gset 0 (preloaded)
    TNEP_ACC(p10, p11, p12, mb4 + 16);       // gset 1 (preloaded)
    {
        float4 g0 = gbase[384], g1 = gbase[400], g2 = gbase[416];   // gset 2
        TNEP_ACC(g0, g1, g2, mb4 + 32);
    }
    {
        float4 g0 = gbase[576], g1 = gbase[592], g2 = gbase[608];   // gset 3
        TNEP_ACC(g0, g1, g2, mb4 + 48);
    }
#undef TNEP_ACC
#undef TNEP_DOT

    // One 64-lane reduction per wave, then cross-wave via LDS.
#pragma unroll
    for (int a = 0; a < 3; ++a)
#pragma unroll
        for (int c = 0; c < 3; ++c) {
            float v = acc[a][c];
#pragma unroll
            for (int s = 1; s < 64; s <<= 1) v += __shfl_xor(v, s, 64);
            if (lane == 0) sacc[w][a * 3 + c] = v;
        }
    __syncthreads();   // B3: sacc, sfpv ready

    if (tid < 9)
        PARTT[(size_t)tid * NA + n] = sacc[0][tid] + sacc[1][tid] + sacc[2][tid] + sacc[3][tid];
    if (tid == 9)
        PARTT[(size_t)9 * NA + n] = sfpv;
}

// -------- Final reduction: 6 blocks, one output element each, 64 threads --------
// Deterministic: fixed lane->n mapping, fixed shfl tree, fixed slot order.
__global__ __launch_bounds__(64) void tnep_reduce6(const float* __restrict__ ws,
                                                   float* __restrict__ out)
{
    const int b    = blockIdx.x;     // 0..5 -> out[b]
    const int lane = threadIdx.x;

    // out0 = slot0 + slot9; out1 = slot4 + slot9; out2 = slot8 + slot9;
    // out3 = slot1; out4 = slot5; out5 = slot6.
    const int slotA_tab[6] = {0, 4, 8, 1, 5, 6};
    const int slotA = slotA_tab[b];
    const bool hasB = (b < 3);

    const float4* pA = reinterpret_cast<const float4*>(ws + (size_t)slotA * NA);
    const float4* pB = reinterpret_cast<const float4*>(ws + (size_t)9 * NA);

    float sA = 0.f, sB = 0.f;
#pragma unroll
    for (int i = 0; i < 16; ++i) {
        float4 v = pA[lane + 64 * i];
        sA += (v.x + v.y) + (v.z + v.w);
    }
    if (hasB) {
#pragma unroll
        for (int i = 0; i < 16; ++i) {
            float4 v = pB[lane + 64 * i];
            sB += (v.x + v.y) + (v.z + v.w);
        }
    }
#pragma unroll
    for (int t = 1; t < 64; t <<= 1) {
        sA += __shfl_xor(sA, t, 64);
        sB += __shfl_xor(sB, t, 64);
    }
    if (lane == 0) out[b] = hasB ? (sA + sB) : sA;
}

// ---------------- Fallback (tiny ws): monolithic with atomics ----------------
__global__ __launch_bounds__(64) void tnep_mono(
    const float* __restrict__ desc,
    const float* __restrict__ grad,
    const int*   __restrict__ gidx,
    const float* __restrict__ pos,
    const int*   __restrict__ Zp,
    const float* __restrict__ box,
    const float* __restrict__ amaskp,
    const float* __restrict__ nmaskp,
    const float* __restrict__ W0,
    const float* __restrict__ b0,
    const float* __restrict__ W1,
    const float* __restrict__ W0p,
    const float* __restrict__ b0p,
    const float* __restrict__ W1p,
    const float* __restrict__ b1p,
    float* __restrict__ out)
{
    const int n    = blockIdx.x;
    const int lane = threadIdx.x;
    const int z    = Zp[n];
    const float amask = amaskp[n];

    __shared__ float sdesc[NQ];
    __shared__ float sW0[NQ * 65];
    __shared__ float sde_da[NH];
    __shared__ float sde_dq[NQ];
    __shared__ float sdr[NM * 4];

    sdesc[lane] = desc[n * NQ + lane];
    const float4* W0v = reinterpret_cast<const float4*>(W0 + (size_t)z * NQ * NH);
#pragma unroll
    for (int i = 0; i < 16; ++i) {
        float4 v = W0v[i * 64 + lane];
        int q  = 4 * i + (lane >> 4);
        int h0 = 4 * (lane & 15);
        float* p = &sW0[q * 65 + h0];
        p[0] = v.x; p[1] = v.y; p[2] = v.z; p[3] = v.w;
    }
    {
        int g = gidx[n * NM + lane];
        float Lx = box[0], Ly = box[4], Lz = box[8];
        float dx = pos[g * 3 + 0] - pos[n * 3 + 0];
        float dy = pos[g * 3 + 1] - pos[n * 3 + 1];
        float dz = pos[g * 3 + 2] - pos[n * 3 + 2];
        dx -= Lx * rintf(dx * (1.0f / Lx));
        dy -= Ly * rintf(dy * (1.0f / Ly));
        dz -= Lz * rintf(dz * (1.0f / Lz));
        float nm = nmaskp[n * NM + lane];
        float wt = -nm * nm;
        sdr[lane * 4 + 0] = wt * dx;
        sdr[lane * 4 + 1] = wt * dy;
        sdr[lane * 4 + 2] = wt * dz;
        sdr[lane * 4 + 3] = 0.0f;
    }
    __syncthreads();

    float a_t = b0 [z * NH + lane];
    float a_p = b0p[z * NH + lane];
    const float* W0prow = W0p + (size_t)z * NQ * NH;
#pragma unroll 8
    for (int q = 0; q < NQ; ++q) {
        float d = sdesc[q];
        a_t = fmaf(d, sW0[q * 65 + lane], a_t);
        a_p = fmaf(d, W0prow[q * NH + lane], a_p);
    }
    float hT = tanhf(a_t) * amask;
    float hP = tanhf(a_p) * amask;
    sde_da[lane] = (1.0f - hT * hT) * W1[z * NH + lane];
    float fp = hP * W1p[z * NH + lane];
#pragma unroll
    for (int s = 1; s < 64; s <<= 1) fp += __shfl_xor(fp, s, 64);
    __syncthreads();

    float dq = 0.0f;
#pragma unroll 8
    for (int h = 0; h < NH; ++h)
        dq = fmaf(sde_da[h], sW0[lane * 65 + h], dq);
    sde_dq[lane] = dq;
    __syncthreads();

    const int msub = lane >> 4;
    const int q4   = lane & 15;
    float4 dq4 = *reinterpret_cast<const float4*>(&sde_dq[4 * q4]);
    float acc[3][3] = {{0.f,0.f,0.f},{0.f,0.f,0.f},{0.f,0.f,0.f}};
    const float4* gbase = reinterpret_cast<const float4*>(grad)
                          + (size_t)n * NM * 48 + msub * 48 + q4;
#pragma unroll
    for (int gset = 0; gset < 16; ++gset) {
        const float4* gp = gbase + gset * 192;
        const int m = gset * 4 + msub;
        float wd0 = sdr[m * 4 + 0];
        float wd1 = sdr[m * 4 + 1];
        float wd2 = sdr[m * 4 + 2];
#pragma unroll
        for (int c = 0; c < 3; ++c) {
            float4 g4 = gp[c * 16];
            float s = fmaf(dq4.x, g4.x, fmaf(dq4.y, g4.y, fmaf(dq4.z, g4.z, dq4.w * g4.w)));
            acc[0][c] = fmaf(s, wd0, acc[0][c]);
            acc[1][c] = fmaf(s, wd1, acc[1][c]);
            acc[2][c] = fmaf(s, wd2, acc[2][c]);
        }
    }
    float fpv = (fp + b1p[0]) * amask;
#pragma unroll
    for (int a = 0; a < 3; ++a)
#pragma unroll
        for (int c = 0; c < 3; ++c) {
            float v = acc[a][c];
#pragma unroll
            for (int s = 1; s < 64; s <<= 1) v += __shfl_xor(v, s, 64);
            acc[a][c] = v;
        }
    if (lane == 0) {
        atomicAdd(out + 0, acc[0][0] + fpv);
        atomicAdd(out + 1, acc[1][1] + fpv);
        atomicAdd(out + 2, acc[2][2] + fpv);
        atomicAdd(out + 3, acc[0][1]);
        atomicAdd(out + 4, acc[1][2]);
        atomicAdd(out + 5, acc[2][0]);
    }
}

__global__ void tnep_zero(float* out)
{
    if (threadIdx.x < 6) out[threadIdx.x] = 0.f;
}

extern "C" void kernel_launch(void* const* d_in, const int* in_sizes, int n_in,
                              void* d_out, int out_size, void* d_ws, size_t ws_size,
                              hipStream_t stream)
{
    const float* desc  = (const float*)d_in[0];
    const float* grad  = (const float*)d_in[1];
    const int*   gidx  = (const int*)  d_in[2];
    const float* pos   = (const float*)d_in[3];
    const int*   Zp    = (const int*)  d_in[4];
    const float* box   = (const float*)d_in[5];
    const float* amask = (const float*)d_in[6];
    const float* nmask = (const float*)d_in[7];
    const float* W0    = (const float*)d_in[8];
    const float* b0    = (const float*)d_in[9];
    const float* W1    = (const float*)d_in[10];
    // d_in[11] = b1 (unused by reference)
    const float* W0p   = (const float*)d_in[12];
    const float* b0p   = (const float*)d_in[13];
    const float* W1p   = (const float*)d_in[14];
    const float* b1p   = (const float*)d_in[15];
    float* out = (float*)d_out;
    float* ws  = (float*)d_ws;

    if (ws_size >= (size_t)WS_FLOATS * sizeof(float)) {
        tnep_fused<<<NA, 256, 0, stream>>>(desc, grad, gidx, pos, Zp, box, amask, nmask,
                                           W0, b0, W1, W0p, b0p, W1p, b1p, ws);
        tnep_reduce6<<<6, 64, 0, stream>>>(ws, out);
    } else {
        tnep_zero<<<1, 64, 0, stream>>>(out);
        tnep_mono<<<NA, 64, 0, stream>>>(desc, grad, gidx, pos, Zp, box, amask, nmask,
                                         W0, b0, W1, W0p, b0p, W1p, b1p, out);
    }
}

// Round 9
// 43.648 us; speedup vs baseline: 1.0357x; 1.0258x over previous
//
#include <hip/hip_runtime.h>
#include <hip/hip_bf16.h>
#include <math.h>

#define NA 4096
#define NB (NA / 2)     // blocks: 2 atoms each
#define NM 64
#define NQ 64
#define NH 64

// ws layout (floats): PARTT[slot][NB]; slots 0..8 = pm[a*3+c], slot 9 = fpv-sum.
#define WS_FLOATS (10 * NB)

// ---------------- Main fused kernel: TWO atoms per 256-thread block ----------------
// Phase 0: preload 6 grad float4 per lane per atom (12 total, in flight across the
// whole preamble); stage W0[z0] and W0[z1] into separate LDS banks; desc/wdr gathers.
// Phase 1 (all 4 waves busy): w0 tensor-ANN A, w1 tensor-ANN B, w2 pol A, w3 pol B.
// Phase 2: stream both atoms' gradients (12 preloaded + 12 fresh float4 per lane),
// one accumulator, ONE epilogue per 2 atoms.
__global__ __launch_bounds__(256, 4) void tnep_fused2(
    const float* __restrict__ desc,
    const float* __restrict__ grad,
    const int*   __restrict__ gidx,
    const float* __restrict__ pos,
    const int*   __restrict__ Zp,
    const float* __restrict__ box,
    const float* __restrict__ amaskp,
    const float* __restrict__ nmaskp,
    const float* __restrict__ W0,
    const float* __restrict__ b0,
    const float* __restrict__ W1,
    const float* __restrict__ W0p,
    const float* __restrict__ b0p,
    const float* __restrict__ W1p,
    const float* __restrict__ b1p,
    float* __restrict__ ws)
{
    const int b    = blockIdx.x;
    const int n0   = 2 * b;
    const int n1   = n0 + 1;
    const int tid  = threadIdx.x;
    const int w    = tid >> 6;
    const int lane = tid & 63;
    const int msub = lane >> 4;
    const int q4   = lane & 15;
    const int z0   = Zp[n0];
    const int z1   = Zp[n1];

    float* PARTT = ws;

    __shared__ float sW0A[NQ * 65];   // pad-65: fwd (stride-1) & bwd (stride-65) conflict-free
    __shared__ float sW0B[NQ * 65];
    __shared__ float sdescA[NQ];
    __shared__ float sdescB[NQ];
    __shared__ float sde_da[2 * NH];  // [0..63]=A (wave0), [64..127]=B (wave1)
    __shared__ float sde_dqA[NQ];
    __shared__ float sde_dqB[NQ];
    __shared__ float swdrA[NM * 4];
    __shared__ float swdrB[NM * 4];
    __shared__ float sacc[4][9];
    __shared__ float sfpvA, sfpvB;

    // ---- Early preloads: 6 float4 per atom per lane, in flight across preamble. ----
    const float4* gA = reinterpret_cast<const float4*>(grad)
                       + ((size_t)n0 * NM + w * 16 + msub) * 48 + q4;
    const float4* gB = gA + (size_t)NM * 48;
    float4 pA0 = gA[0],   pA1 = gA[16],  pA2 = gA[32];    // A gset 0
    float4 pA3 = gA[192], pA4 = gA[208], pA5 = gA[224];   // A gset 1
    float4 pB0 = gB[0],   pB1 = gB[16],  pB2 = gB[32];    // B gset 0
    float4 pB3 = gB[192], pB4 = gB[208], pB5 = gB[224];   // B gset 1

    // Cooperative stage of W0[z0] and W0[z1] (16 KB each), all 256 threads.
    const float4* W0vA = reinterpret_cast<const float4*>(W0 + (size_t)z0 * NQ * NH);
    const float4* W0vB = reinterpret_cast<const float4*>(W0 + (size_t)z1 * NQ * NH);
#pragma unroll
    for (int i = 0; i < 4; ++i) {
        int f = i * 256 + tid;
        float4 vA = W0vA[f];
        float4 vB = W0vB[f];
        int q  = f >> 4;
        int h0 = (f & 15) * 4;
        float* pa = &sW0A[q * 65 + h0];
        pa[0] = vA.x; pa[1] = vA.y; pa[2] = vA.z; pa[3] = vA.w;
        float* pb = &sW0B[q * 65 + h0];
        pb[0] = vB.x; pb[1] = vB.y; pb[2] = vB.z; pb[3] = vB.w;
    }
    if (w == 0) sdescA[lane] = desc[n0 * NQ + lane];
    if (w == 1) sdescB[lane] = desc[n1 * NQ + lane];
    if (w == 2 || w == 3) {
        // Minimal-image displacement scalars, -nmask^2 folded in (lane = m).
        const int   nn  = (w == 2) ? n0 : n1;
        float*      sdr = (w == 2) ? swdrA : swdrB;
        int g = gidx[nn * NM + lane];
        float Lx = box[0], Ly = box[4], Lz = box[8];
        float dx = pos[g * 3 + 0] - pos[nn * 3 + 0];
        float dy = pos[g * 3 + 1] - pos[nn * 3 + 1];
        float dz = pos[g * 3 + 2] - pos[nn * 3 + 2];
        dx -= Lx * rintf(dx * (1.0f / Lx));   // rintf = round-half-even = jnp.round
        dy -= Ly * rintf(dy * (1.0f / Ly));
        dz -= Lz * rintf(dz * (1.0f / Lz));
        float nm = nmaskp[nn * NM + lane];
        float wt = -nm * nm;
        sdr[lane * 4 + 0] = wt * dx;
        sdr[lane * 4 + 1] = wt * dy;
        sdr[lane * 4 + 2] = wt * dz;
        sdr[lane * 4 + 3] = 0.0f;
    }
    __syncthreads();   // B1: sW0A/B, sdescA/B, swdrA/B ready

    if (w <= 1) {
        // Tensor ANN fwd + bwd for atom A (w0) / B (w1); wave-internal LDS use.
        const int    nn   = (w == 0) ? n0 : n1;
        const int    zz   = (w == 0) ? z0 : z1;
        const float* sW0x = (w == 0) ? sW0A : sW0B;
        const float* sdx  = (w == 0) ? sdescA : sdescB;
        float*       sda  = sde_da + w * NH;
        float*       sdq  = (w == 0) ? sde_dqA : sde_dqB;
        float amask = amaskp[nn];
        float a_t = b0[zz * NH + lane];
#pragma unroll 8
        for (int q = 0; q < NQ; ++q)
            a_t = fmaf(sdx[q], sW0x[q * 65 + lane], a_t);
        float hT = tanhf(a_t) * amask;
        sda[lane] = (1.0f - hT * hT) * W1[zz * NH + lane];   // lane = h
        float dq = 0.0f;
#pragma unroll 8
        for (int h = 0; h < NH; ++h)                          // lane = q
            dq = fmaf(sda[h], sW0x[lane * 65 + h], dq);
        sdq[lane] = dq;
    } else {
        // Pol ANN for atom A (w2) / B (w3): global reads only (L2-resident).
        const int nn = (w == 2) ? n0 : n1;
        const int zz = (w == 2) ? z0 : z1;
        float amask = amaskp[nn];
        float a_p = b0p[zz * NH + lane];
        const float* W0prow = W0p + (size_t)zz * NQ * NH;
        const float* drow   = desc + (size_t)nn * NQ;
#pragma unroll 8
        for (int q = 0; q < NQ; ++q)
            a_p = fmaf(drow[q], W0prow[q * NH + lane], a_p);
        float hP = tanhf(a_p) * amask;
        float fp = hP * W1p[zz * NH + lane];
#pragma unroll
        for (int s = 1; s < 64; s <<= 1) fp += __shfl_xor(fp, s, 64);
        if (lane == 0) {
            float v = (fp + b1p[0]) * amask;
            if (w == 2) sfpvA = v; else sfpvB = v;
        }
    }
    __syncthreads();   // B2: sde_dqA/B, sfpvA/B ready

    // ---- Streaming phase: wave w owns m in [w*16, w*16+16); lane = msub*16+q4. ----
    float4 dq4A = *reinterpret_cast<const float4*>(&sde_dqA[4 * q4]);
    float4 dq4B = *reinterpret_cast<const float4*>(&sde_dqB[4 * q4]);
    float acc[3][3] = {{0.f,0.f,0.f},{0.f,0.f,0.f},{0.f,0.f,0.f}};
    const int mb4 = (w * 16 + msub) * 4;

    // Fresh loads for gsets 2,3 of both atoms — issued before any FMA.
    float4 a20 = gA[384], a21 = gA[400], a22 = gA[416];
    float4 a30 = gA[576], a31 = gA[592], a32 = gA[608];
    float4 b20 = gB[384], b21 = gB[400], b22 = gB[416];
    float4 b30 = gB[576], b31 = gB[592], b32 = gB[608];

#define TNEP_DOT(dq4, g4) fmaf((dq4).x, (g4).x, fmaf((dq4).y, (g4).y, fmaf((dq4).z, (g4).z, (dq4).w * (g4).w)))
#define TNEP_ACC(dq4, sdr, g0, g1, g2, widx)                                    \
    {                                                                           \
        float wd0 = (sdr)[(widx) + 0], wd1 = (sdr)[(widx) + 1], wd2 = (sdr)[(widx) + 2]; \
        float s0 = TNEP_DOT(dq4, g0), s1 = TNEP_DOT(dq4, g1), s2 = TNEP_DOT(dq4, g2); \
        acc[0][0] = fmaf(s0, wd0, acc[0][0]);                                   \
        acc[1][0] = fmaf(s0, wd1, acc[1][0]);                                   \
        acc[2][0] = fmaf(s0, wd2, acc[2][0]);                                   \
        acc[0][1] = fmaf(s1, wd0, acc[0][1]);                                   \
        acc[1][1] = fmaf(s1, wd1, acc[1][1]);                                   \
        acc[2][1] = fmaf(s1, wd2, acc[2][1]);                                   \
        acc[0][2] = fmaf(s2, wd0, acc[0][2]);                                   \
        acc[1][2] = fmaf(s2, wd1, acc[1][2]);                                   \
        acc[2][2] = fmaf(s2, wd2, acc[2][2]);                                   \
    }

    // Preloaded fragments first (arrived long ago; frees 48 VGPRs early).
    TNEP_ACC(dq4A, swdrA, pA0, pA1, pA2, mb4);
    TNEP_ACC(dq4A, swdrA, pA3, pA4, pA5, mb4 + 16);
    TNEP_ACC(dq4B, swdrB, pB0, pB1, pB2, mb4);
    TNEP_ACC(dq4B, swdrB, pB3, pB4, pB5, mb4 + 16);
    // Fresh fragments in issue order.
    TNEP_ACC(dq4A, swdrA, a20, a21, a22, mb4 + 32);
    TNEP_ACC(dq4A, swdrA, a30, a31, a32, mb4 + 48);
    TNEP_ACC(dq4B, swdrB, b20, b21, b22, mb4 + 32);
    TNEP_ACC(dq4B, swdrB, b30, b31, b32, mb4 + 48);
#undef TNEP_ACC
#undef TNEP_DOT

    // One 64-lane reduction per wave, then cross-wave via LDS.
#pragma unroll
    for (int a = 0; a < 3; ++a)
#pragma unroll
        for (int c = 0; c < 3; ++c) {
            float v = acc[a][c];
#pragma unroll
            for (int s = 1; s < 64; s <<= 1) v += __shfl_xor(v, s, 64);
            if (lane == 0) sacc[w][a * 3 + c] = v;
        }
    __syncthreads();   // B3: sacc, sfpvA/B ready

    if (tid < 9)
        PARTT[(size_t)tid * NB + b] = sacc[0][tid] + sacc[1][tid] + sacc[2][tid] + sacc[3][tid];
    if (tid == 9)
        PARTT[(size_t)9 * NB + b] = sfpvA + sfpvB;
}

// -------- Final reduction: 6 blocks (one output element each), 256 threads --------
// Deterministic: fixed thread->entry mapping, fixed shfl tree, fixed slot order.
__global__ __launch_bounds__(256) void tnep_reduce6(const float* __restrict__ ws,
                                                    float* __restrict__ out)
{
    __shared__ float sred[4];
    const int bo   = blockIdx.x;     // 0..5 -> out[bo]
    const int tid  = threadIdx.x;
    const int w    = tid >> 6;
    const int lane = tid & 63;

    // out0 = slot0 + slot9; out1 = slot4 + slot9; out2 = slot8 + slot9;
    // out3 = slot1; out4 = slot5; out5 = slot6.
    const int slotA_tab[6] = {0, 4, 8, 1, 5, 6};
    const int slotA = slotA_tab[bo];
    const bool hasB = (bo < 3);

    const float4* pA = reinterpret_cast<const float4*>(ws + (size_t)slotA * NB);
    const float4* pB = reinterpret_cast<const float4*>(ws + (size_t)9 * NB);

    // NB = 2048 floats = 512 float4; 256 threads x 2 float4.
    float4 v0 = pA[tid], v1 = pA[tid + 256];
    float s = ((v0.x + v0.y) + (v0.z + v0.w)) + ((v1.x + v1.y) + (v1.z + v1.w));
    if (hasB) {
        float4 u0 = pB[tid], u1 = pB[tid + 256];
        s += ((u0.x + u0.y) + (u0.z + u0.w)) + ((u1.x + u1.y) + (u1.z + u1.w));
    }
#pragma unroll
    for (int t = 1; t < 64; t <<= 1) s += __shfl_xor(s, t, 64);
    if (lane == 0) sred[w] = s;
    __syncthreads();
    if (tid == 0) out[bo] = (sred[0] + sred[1]) + (sred[2] + sred[3]);
}

// ---------------- Fallback (tiny ws): monolithic with atomics ----------------
__global__ __launch_bounds__(64) void tnep_mono(
    const float* __restrict__ desc,
    const float* __restrict__ grad,
    const int*   __restrict__ gidx,
    const float* __restrict__ pos,
    const int*   __restrict__ Zp,
    const float* __restrict__ box,
    const float* __restrict__ amaskp,
    const float* __restrict__ nmaskp,
    const float* __restrict__ W0,
    const float* __restrict__ b0,
    const float* __restrict__ W1,
    const float* __restrict__ W0p,
    const float* __restrict__ b0p,
    const float* __restrict__ W1p,
    const float* __restrict__ b1p,
    float* __restrict__ out)
{
    const int n    = blockIdx.x;
    const int lane = threadIdx.x;
    const int z    = Zp[n];
    const float amask = amaskp[n];

    __shared__ float sdesc[NQ];
    __shared__ float sW0[NQ * 65];
    __shared__ float sde_da[NH];
    __shared__ float sde_dq[NQ];
    __shared__ float sdr[NM * 4];

    sdesc[lane] = desc[n * NQ + lane];
    const float4* W0v = reinterpret_cast<const float4*>(W0 + (size_t)z * NQ * NH);
#pragma unroll
    for (int i = 0; i < 16; ++i) {
        float4 v = W0v[i * 64 + lane];
        int q  = 4 * i + (lane >> 4);
        int h0 = 4 * (lane & 15);
        float* p = &sW0[q * 65 + h0];
        p[0] = v.x; p[1] = v.y; p[2] = v.z; p[3] = v.w;
    }
    {
        int g = gidx[n * NM + lane];
        float Lx = box[0], Ly = box[4], Lz = box[8];
        float dx = pos[g * 3 + 0] - pos[n * 3 + 0];
        float dy = pos[g * 3 + 1] - pos[n * 3 + 1];
        float dz = pos[g * 3 + 2] - pos[n * 3 + 2];
        dx -= Lx * rintf(dx * (1.0f / Lx));
        dy -= Ly * rintf(dy * (1.0f / Ly));
        dz -= Lz * rintf(dz * (1.0f / Lz));
        float nm = nmaskp[n * NM + lane];
        float wt = -nm * nm;
        sdr[lane * 4 + 0] = wt * dx;
        sdr[lane * 4 + 1] = wt * dy;
        sdr[lane * 4 + 2] = wt * dz;
        sdr[lane * 4 + 3] = 0.0f;
    }
    __syncthreads();

    float a_t = b0 [z * NH + lane];
    float a_p = b0p[z * NH + lane];
    const float* W0prow = W0p + (size_t)z * NQ * NH;
#pragma unroll 8
    for (int q = 0; q < NQ; ++q) {
        float d = sdesc[q];
        a_t = fmaf(d, sW0[q * 65 + lane], a_t);
        a_p = fmaf(d, W0prow[q * NH + lane], a_p);
    }
    float hT = tanhf(a_t) * amask;
    float hP = tanhf(a_p) * amask;
    sde_da[lane] = (1.0f - hT * hT) * W1[z * NH + lane];
    float fp = hP * W1p[z * NH + lane];
#pragma unroll
    for (int s = 1; s < 64; s <<= 1) fp += __shfl_xor(fp, s, 64);
    __syncthreads();

    float dq = 0.0f;
#pragma unroll 8
    for (int h = 0; h < NH; ++h)
        dq = fmaf(sde_da[h], sW0[lane * 65 + h], dq);
    sde_dq[lane] = dq;
    __syncthreads();

    const int msub = lane >> 4;
    const int q4   = lane & 15;
    float4 dq4 = *reinterpret_cast<const float4*>(&sde_dq[4 * q4]);
    float acc[3][3] = {{0.f,0.f,0.f},{0.f,0.f,0.f},{0.f,0.f,0.f}};
    const float4* gbase = reinterpret_cast<const float4*>(grad)
                          + (size_t)n * NM * 48 + msub * 48 + q4;
#pragma unroll
    for (int gset = 0; gset < 16; ++gset) {
        const float4* gp = gbase + gset * 192;
        const int m = gset * 4 + msub;
        float wd0 = sdr[m * 4 + 0];
        float wd1 = sdr[m * 4 + 1];
        float wd2 = sdr[m * 4 + 2];
#pragma unroll
        for (int c = 0; c < 3; ++c) {
            float4 g4 = gp[c * 16];
            float s = fmaf(dq4.x, g4.x, fmaf(dq4.y, g4.y, fmaf(dq4.z, g4.z, dq4.w * g4.w)));
            acc[0][c] = fmaf(s, wd0, acc[0][c]);
            acc[1][c] = fmaf(s, wd1, acc[1][c]);
            acc[2][c] = fmaf(s, wd2, acc[2][c]);
        }
    }
    float fpv = (fp + b1p[0]) * amask;
#pragma unroll
    for (int a = 0; a < 3; ++a)
#pragma unroll
        for (int c = 0; c < 3; ++c) {
            float v = acc[a][c];
#pragma unroll
            for (int s = 1; s < 64; s <<= 1) v += __shfl_xor(v, s, 64);
            acc[a][c] = v;
        }
    if (lane == 0) {
        atomicAdd(out + 0, acc[0][0] + fpv);
        atomicAdd(out + 1, acc[1][1] + fpv);
        atomicAdd(out + 2, acc[2][2] + fpv);
        atomicAdd(out + 3, acc[0][1]);
        atomicAdd(out + 4, acc[1][2]);
        atomicAdd(out + 5, acc[2][0]);
    }
}

__global__ void tnep_zero(float* out)
{
    if (threadIdx.x < 6) out[threadIdx.x] = 0.f;
}

extern "C" void kernel_launch(void* const* d_in, const int* in_sizes, int n_in,
                              void* d_out, int out_size, void* d_ws, size_t ws_size,
                              hipStream_t stream)
{
    const float* desc  = (const float*)d_in[0];
    const float* grad  = (const float*)d_in[1];
    const int*   gidx  = (const int*)  d_in[2];
    const float* pos   = (const float*)d_in[3];
    const int*   Zp    = (const int*)  d_in[4];
    const float* box   = (const float*)d_in[5];
    const float* amask = (const float*)d_in[6];
    const float* nmask = (const float*)d_in[7];
    const float* W0    = (const float*)d_in[8];
    const float* b0    = (const float*)d_in[9];
    const float* W1    = (const float*)d_in[10];
    // d_in[11] = b1 (unused by reference)
    const float* W0p   = (const float*)d_in[12];
    const float* b0p   = (const float*)d_in[13];
    const float* W1p   = (const float*)d_in[14];
    const float* b1p   = (const float*)d_in[15];
    float* out = (float*)d_out;
    float* ws  = (float*)d_ws;

    if (ws_size >= (size_t)WS_FLOATS * sizeof(float)) {
        tnep_fused2<<<NB, 256, 0, stream>>>(desc, grad, gidx, pos, Zp, box, amask, nmask,
                                            W0, b0, W1, W0p, b0p, W1p, b1p, ws);
        tnep_reduce6<<<6, 256, 0, stream>>>(ws, out);
    } else {
        tnep_zero<<<1, 64, 0, stream>>>(out);
        tnep_mono<<<NA, 64, 0, stream>>>(desc, grad, gidx, pos, Zp, box, amask, nmask,
                                         W0, b0, W1, W0p, b0p, W1p, b1p, out);
    }
}